// Round 1
// baseline (208.715 us; speedup 1.0000x reference)
//
#include <hip/hip_runtime.h>

// DecoderAttention: only edges into the B=64 global nodes contribute to the
// output (q is zero elsewhere and only out[glob_idx] is read). ~512 of the
// 320000 edges matter. We bucket those edges per global node, then one block
// per global node computes k/v rows on the fly, does the per-head softmax,
// aggregates v, and applies the WO projection — fully fused.

#define Dm 256
#define Hh 4
#define DKk 64
#define MAXDEG 512

__global__ void k_init(int* __restrict__ inv, int nv, int* __restrict__ bcnt, int b) {
    int i = blockIdx.x * blockDim.x + threadIdx.x;
    if (i < nv) inv[i] = -1;
    if (i < b) bcnt[i] = 0;
}

// One block per global row: Q[b][j] = dot(query[b], WQ[j]); also build inverse map.
__global__ __launch_bounds__(256)
void k_qproj(const float* __restrict__ query, const float* __restrict__ WQ,
             const int* __restrict__ glob_idx, float* __restrict__ Q,
             int* __restrict__ inv) {
    int bb = blockIdx.x;
    int j = threadIdx.x;
    const float4* qr = reinterpret_cast<const float4*>(query + (size_t)bb * Dm);
    const float4* wr = reinterpret_cast<const float4*>(WQ + (size_t)j * Dm);
    float acc = 0.f;
#pragma unroll
    for (int c = 0; c < Dm / 4; ++c) {
        float4 a = qr[c], w = wr[c];
        acc += a.x * w.x + a.y * w.y + a.z * w.z + a.w * w.w;
    }
    Q[bb * Dm + j] = acc;
    if (j == 0) inv[glob_idx[bb]] = bb;
}

__global__ void k_compact(const int* __restrict__ src, const int* __restrict__ dst,
                          const int* __restrict__ inv, int* __restrict__ bcnt,
                          int* __restrict__ bucket, int ne) {
    int e = blockIdx.x * blockDim.x + threadIdx.x;
    if (e >= ne) return;
    int ii = inv[dst[e]];
    if (ii >= 0) {
        int pos = atomicAdd(&bcnt[ii], 1);
        if (pos < MAXDEG) bucket[ii * MAXDEG + pos] = src[e];
    }
}

// One block (256 thr = 4 waves = 4 heads x 64 dims) per global node.
__global__ __launch_bounds__(256)
void k_node(const float* __restrict__ x, const float* __restrict__ WK,
            const float* __restrict__ WV, const float* __restrict__ WO,
            const float* __restrict__ Q, const int* __restrict__ bcnt,
            const int* __restrict__ bucket, float* __restrict__ out) {
    int i = blockIdx.x;
    int t = threadIdx.x;      // t = h*64 + d
    int h = t >> 6;           // wave id == head id
    int lane = t & 63;
    __shared__ float s_s[MAXDEG * Hh];
    __shared__ float s_out[Dm];
    __shared__ float s_den[Hh];

    int deg = bcnt[i];
    if (deg > MAXDEG) deg = MAXDEG;
    float qv = Q[i * Dm + t];
    const float4* wk = reinterpret_cast<const float4*>(WK + (size_t)t * Dm);
    const float4* wv = reinterpret_cast<const float4*>(WV + (size_t)t * Dm);
    const int* bkt = bucket + i * MAXDEG;

    // Pass 1: per-edge, per-head scores s = (q . k[src]) / sqrt(DK)
    for (int e = 0; e < deg; ++e) {
        int sv = bkt[e];
        const float4* xr = reinterpret_cast<const float4*>(x + (size_t)sv * Dm);
        float acc = 0.f;
#pragma unroll
        for (int c = 0; c < Dm / 4; ++c) {
            float4 a = xr[c], w = wk[c];
            acc += a.x * w.x + a.y * w.y + a.z * w.z + a.w * w.w;
        }
        float p = acc * qv;   // q[i][t] * k[sv][t], reduce over the 64 dims of this head
#pragma unroll
        for (int off = 32; off >= 1; off >>= 1) p += __shfl_xor(p, off, 64);
        if (lane == 0) s_s[e * Hh + h] = p * 0.125f;  // 1/sqrt(64)
    }
    __syncthreads();

    // Stable softmax over in-edges, per head (deg ~ 8, serial is fine)
    if (t < Hh) {
        float m = -INFINITY;
        for (int e = 0; e < deg; ++e) m = fmaxf(m, s_s[e * Hh + t]);
        float dn = 0.f;
        for (int e = 0; e < deg; ++e) {
            float w = expf(s_s[e * Hh + t] - m);
            s_s[e * Hh + t] = w;
            dn += w;
        }
        s_den[t] = dn;
    }
    __syncthreads();

    // Pass 2: weighted aggregation of v[src]
    float acc = 0.f;
    for (int e = 0; e < deg; ++e) {
        int sv = bkt[e];
        const float4* xr = reinterpret_cast<const float4*>(x + (size_t)sv * Dm);
        float vv = 0.f;
#pragma unroll
        for (int c = 0; c < Dm / 4; ++c) {
            float4 a = xr[c], w = wv[c];
            vv += a.x * w.x + a.y * w.y + a.z * w.z + a.w * w.w;
        }
        acc += s_s[e * Hh + h] * vv;
    }
    float o = (deg > 0) ? acc / s_den[h] : 0.f;   // deg==0 -> out row is 0 (matches ref)
    s_out[t] = o;
    __syncthreads();

    // Output projection: r[i][t] = dot(out_row, WO[t])
    const float4* wo = reinterpret_cast<const float4*>(WO + (size_t)t * Dm);
    const float4* so = reinterpret_cast<const float4*>(s_out);
    float r = 0.f;
#pragma unroll
    for (int c = 0; c < Dm / 4; ++c) {
        float4 a = so[c], w = wo[c];
        r += a.x * w.x + a.y * w.y + a.z * w.z + a.w * w.w;
    }
    out[i * Dm + t] = r;
}

extern "C" void kernel_launch(void* const* d_in, const int* in_sizes, int n_in,
                              void* d_out, int out_size, void* d_ws, size_t ws_size,
                              hipStream_t stream) {
    const float* query = (const float*)d_in[0];
    const float* x     = (const float*)d_in[1];
    const float* WQ    = (const float*)d_in[2];
    const float* WK    = (const float*)d_in[3];
    const float* WV    = (const float*)d_in[4];
    const float* WO    = (const float*)d_in[5];
    const int*   src   = (const int*)d_in[6];
    const int*   dst   = (const int*)d_in[7];
    const int*   glob  = (const int*)d_in[8];

    int B  = in_sizes[8];
    int NV = in_sizes[1] / Dm;
    int NE = in_sizes[6];

    // Workspace layout (all 4-byte elems): Q[B*Dm] | inv[NV] | bcnt[B] | bucket[B*MAXDEG]
    float* Q    = (float*)d_ws;
    int*   inv  = (int*)(Q + (size_t)B * Dm);
    int*   bcnt = inv + NV;
    int*   bucket = bcnt + B;
    float* out = (float*)d_out;

    int initN = NV > B ? NV : B;
    k_init<<<(initN + 255) / 256, 256, 0, stream>>>(inv, NV, bcnt, B);
    k_qproj<<<B, 256, 0, stream>>>(query, WQ, glob, Q, inv);
    k_compact<<<(NE + 255) / 256, 256, 0, stream>>>(src, dst, inv, bcnt, bucket, NE);
    k_node<<<B, 256, 0, stream>>>(x, WK, WV, WO, Q, bcnt, bucket, out);
}